// Round 8
// baseline (2279.162 us; speedup 1.0000x reference)
//
#include <hip/hip_runtime.h>

// BiLSTM: B=2048, T=200, D=U=128, 2 layers, bidirectional, merge='ave'.
// R7: single barrier per step via LAYER PIPELINING: iter t computes
// L0(t) and L1(t-1) together (both read h0(t-1); L1 also h1(t-2)).
// ALL FOUR weight matrices register-resident (256 regs/lane fp16 frags;
// 2 waves/SIMD so ~390 total regs/wave fits the 2048-reg SIMD file).
// LDS: only h0/h1/x double buffers = 24KB static. Raw lgkm-only barriers.
// Epilogue computes final L1(T-1). Out via atomicAdd 0.5*h (commutative).

#define NB   2048
#define NTT  200
#define ND   128
#define NTHR 512   // 8 waves

typedef _Float16 f16x8 __attribute__((ext_vector_type(8)));
typedef _Float16 f16x4 __attribute__((ext_vector_type(4)));
typedef float    f32x4 __attribute__((ext_vector_type(4)));

#define BARRIER() asm volatile("s_waitcnt lgkmcnt(0)\n\ts_barrier" ::: "memory")

__device__ __forceinline__ float rcp_f(float x){ return __builtin_amdgcn_rcpf(x); }
__device__ __forceinline__ float sigm(float x){ return rcp_f(1.f + __expf(-x)); }
__device__ __forceinline__ float tanh_f(float x){ return 1.f - 2.f*rcp_f(__expf(2.f*x) + 1.f); }

// ---- weight repack to fp16 frags: pk[dir][m][CT][ks][lane][8], m={W0,U0,W1,U1}
// element (lane l, slot j) = src[layer][k][col], k=ks*32+(l>>4)*8+j, col=CT*16+(l&15)
__global__ void __launch_bounds__(256)
repack_w(const float* __restrict__ Wf, const float* __restrict__ Uf,
         const float* __restrict__ Wb, const float* __restrict__ Ub,
         _Float16* __restrict__ pk)
{
  int flat = blockIdx.x*256 + threadIdx.x;        // 0 .. 524287
  int j  = flat & 7;
  int lx = (flat >> 3)  & 63;
  int ks = (flat >> 9)  & 3;
  int CT = (flat >> 11) & 31;
  int m  = (flat >> 16) & 3;
  int dr = (flat >> 18) & 1;
  int k  = ks*32 + (lx >> 4)*8 + j;
  int cc = CT*16 + (lx & 15);
  const float* src = dr ? ((m & 1) ? Ub : Wb) : ((m & 1) ? Uf : Wf);
  int layer = m >> 1;
  pk[flat] = (_Float16)src[((size_t)layer*ND + k)*512 + cc];
}

__global__ void __launch_bounds__(NTHR, 2)
bilstm_mfma(const float* __restrict__ x,
            const float* __restrict__ bf_, const float* __restrict__ bb_,
            const _Float16* __restrict__ pk,
            float* __restrict__ out)
{
  __shared__ __align__(16) _Float16 h0a[4096];  // 2 bufs x 2048
  __shared__ __align__(16) _Float16 h1a[4096];  // 2 bufs x 2048
  __shared__ __align__(16) _Float16 xb [4096];  // 2 bufs x 2048

  const int tid = threadIdx.x;
  const int dir = blockIdx.y;
  const int b0  = blockIdx.x * 16;
  const int w    = tid >> 6;         // wave 0..7
  const int l    = tid & 63;
  const int col  = l & 15;
  const int kg   = l >> 4;           // 0..3
  const int unit = 16*w + col;

  const f16x8* PKH = (const f16x8*)pk;

  // ---- resident weight fragments: 4 matrices x 4 CT x 4 ks = 256 regs/lane
  f16x8 w0r[4][4], u0r[4][4], w1r[4][4], u1r[4][4];   // [i][ks]
  #pragma unroll
  for (int i = 0; i < 4; ++i)
    #pragma unroll
    for (int ks = 0; ks < 4; ++ks){
      w0r[i][ks] = PKH[(size_t)(((dir*4 + 0)*32 + (w + 8*i))*4 + ks)*64 + l];
      u0r[i][ks] = PKH[(size_t)(((dir*4 + 1)*32 + (w + 8*i))*4 + ks)*64 + l];
      w1r[i][ks] = PKH[(size_t)(((dir*4 + 2)*32 + (w + 8*i))*4 + ks)*64 + l];
      u1r[i][ks] = PKH[(size_t)(((dir*4 + 3)*32 + (w + 8*i))*4 + ks)*64 + l];
    }

  const float* Bias = dir ? bb_ : bf_;
  float bia0[4], bia1[4];
  #pragma unroll
  for (int i = 0; i < 4; ++i){
    bia0[i] = Bias[unit + 128*i];
    bia1[i] = Bias[512 + unit + 128*i];
  }

  // zero initial h state (both buffers)
  for (int i = tid; i < 4096; i += NTHR){ h0a[i] = (_Float16)0.f; h1a[i] = (_Float16)0.f; }

  const int er = tid >> 5;           // 0..15
  const int ej = (tid & 31) * 4;     // 0..124
  const size_t xbase = ((size_t)(b0 + er)*NTT)*ND + ej;
  const int xidx = ((ej >> 3) << 7) + (er << 3) + (ej & 7);
  const int hbase = ((unit >> 3) << 7) + (unit & 7);

  // prologue: stage x(t=0) into xb[0]
  {
    const int te0 = dir ? (NTT-1) : 0;
    float4 xv = *(const float4*)(x + xbase + (size_t)te0*ND);
    float vv[4] = {xv.x, xv.y, xv.z, xv.w};
    f16x4 hx;
    #pragma unroll
    for (int q = 0; q < 4; ++q) hx[q] = (_Float16)vv[q];
    *(f16x4*)(xb + xidx) = hx;
  }

  float c0[4] = {0,0,0,0}, c1[4] = {0,0,0,0};

  __syncthreads();

  for (int t = 0; t < NTT; ++t){
    const int te = dir ? (NTT-1-t) : t;
    const int rb = t & 1, wb = rb ^ 1;

    // issue x(t+1) load first (oldest vm op; staged at step end)
    const int tn = (t + 1 < NTT) ? (t + 1) : t;
    const int ten = dir ? (NTT-1-tn) : tn;
    float4 xv = *(const float4*)(x + xbase + (size_t)ten*ND);

    // ---- front-loaded LDS reads (shared ah0 feeds both layers)
    f16x8 ax[4], ah0[4], ah1[4];
    #pragma unroll
    for (int ks = 0; ks < 4; ++ks){
      ax [ks] = *(const f16x8*)(xb  + rb*2048 + ks*512 + l*8);
      ah0[ks] = *(const f16x8*)(h0a + rb*2048 + ks*512 + l*8);
      ah1[ks] = *(const f16x8*)(h1a + rb*2048 + ks*512 + l*8);
    }

    // ---- 64 MFMA, 8 independent chains: L0(t) and L1(t-1)
    f32x4 acc0[4], acc1[4];
    #pragma unroll
    for (int i = 0; i < 4; ++i){
      acc0[i] = (f32x4){bia0[i], bia0[i], bia0[i], bia0[i]};
      acc1[i] = (f32x4){bia1[i], bia1[i], bia1[i], bia1[i]};
    }
    #pragma unroll
    for (int ks = 0; ks < 4; ++ks)
      #pragma unroll
      for (int i = 0; i < 4; ++i){
        acc0[i] = __builtin_amdgcn_mfma_f32_16x16x32_f16(ax [ks], w0r[i][ks], acc0[i], 0, 0, 0);
        acc0[i] = __builtin_amdgcn_mfma_f32_16x16x32_f16(ah0[ks], u0r[i][ks], acc0[i], 0, 0, 0);
        acc1[i] = __builtin_amdgcn_mfma_f32_16x16x32_f16(ah0[ks], w1r[i][ks], acc1[i], 0, 0, 0);
        acc1[i] = __builtin_amdgcn_mfma_f32_16x16x32_f16(ah1[ks], u1r[i][ks], acc1[i], 0, 0, 0);
      }

    // ---- cell updates
    #pragma unroll
    for (int q = 0; q < 4; ++q){
      float ig = sigm(acc0[0][q]);
      float fg = sigm(acc0[1][q]);
      float gg = tanh_f(acc0[2][q]);
      float og = sigm(acc0[3][q]);
      float cv = __builtin_fmaf(fg, c0[q], ig*gg);
      c0[q] = cv;
      float hh = og * tanh_f(cv);
      h0a[wb*2048 + hbase + (kg*4 + q)*8] = (_Float16)hh;
    }
    if (t > 0){
      const int teo = dir ? (NTT-t) : (t-1);   // time index t-1
      #pragma unroll
      for (int q = 0; q < 4; ++q){
        float ig = sigm(acc1[0][q]);
        float fg = sigm(acc1[1][q]);
        float gg = tanh_f(acc1[2][q]);
        float og = sigm(acc1[3][q]);
        float cv = __builtin_fmaf(fg, c1[q], ig*gg);
        c1[q] = cv;
        float hh = og * tanh_f(cv);
        h1a[wb*2048 + hbase + (kg*4 + q)*8] = (_Float16)hh;
        atomicAdd(out + ((size_t)(b0 + kg*4 + q)*NTT + teo)*ND + unit, 0.5f*hh);
      }
    }
    // t==0: h1a[wb] stays zero (= h1(-1)), c1 stays 0. acc1 discarded.

    // stage x(t+1) into xb[wb]
    {
      float vv[4] = {xv.x, xv.y, xv.z, xv.w};
      f16x4 hx;
      #pragma unroll
      for (int q = 0; q < 4; ++q) hx[q] = (_Float16)vv[q];
      *(f16x4*)(xb + wb*2048 + xidx) = hx;
    }

    BARRIER();   // single barrier: h0(t), h1(t-1), x(t+1) ready for iter t+1
  }

  // ---- epilogue: L1(NTT-1). After final barrier, h0(NTT-1) and h1(NTT-2)
  // sit in buffers rb = NTT&1 = 0.
  {
    const int rb = NTT & 1;
    f16x8 ah0[4], ah1[4];
    #pragma unroll
    for (int ks = 0; ks < 4; ++ks){
      ah0[ks] = *(const f16x8*)(h0a + rb*2048 + ks*512 + l*8);
      ah1[ks] = *(const f16x8*)(h1a + rb*2048 + ks*512 + l*8);
    }
    f32x4 acc1[4];
    #pragma unroll
    for (int i = 0; i < 4; ++i) acc1[i] = (f32x4){bia1[i], bia1[i], bia1[i], bia1[i]};
    #pragma unroll
    for (int ks = 0; ks < 4; ++ks)
      #pragma unroll
      for (int i = 0; i < 4; ++i){
        acc1[i] = __builtin_amdgcn_mfma_f32_16x16x32_f16(ah0[ks], w1r[i][ks], acc1[i], 0, 0, 0);
        acc1[i] = __builtin_amdgcn_mfma_f32_16x16x32_f16(ah1[ks], u1r[i][ks], acc1[i], 0, 0, 0);
      }
    const int teo = dir ? 0 : (NTT-1);
    #pragma unroll
    for (int q = 0; q < 4; ++q){
      float ig = sigm(acc1[0][q]);
      float fg = sigm(acc1[1][q]);
      float gg = tanh_f(acc1[2][q]);
      float og = sigm(acc1[3][q]);
      float cv = __builtin_fmaf(fg, c1[q], ig*gg);
      float hh = og * tanh_f(cv);
      atomicAdd(out + ((size_t)(b0 + kg*4 + q)*NTT + teo)*ND + unit, 0.5f*hh);
    }
  }
}

extern "C" void kernel_launch(void* const* d_in, const int* in_sizes, int n_in,
                              void* d_out, int out_size, void* d_ws, size_t ws_size,
                              hipStream_t stream)
{
  const float* x  = (const float*)d_in[0];
  const float* Wf = (const float*)d_in[1];
  const float* Uf = (const float*)d_in[2];
  const float* bf = (const float*)d_in[3];
  const float* Wb = (const float*)d_in[4];
  const float* Ub = (const float*)d_in[5];
  const float* bb = (const float*)d_in[6];
  float* out = (float*)d_out;

  _Float16* pk = (_Float16*)d_ws;   // 1 MB packed fp16 weights

  repack_w<<<2048, 256, 0, stream>>>(Wf, Uf, Wb, Ub, pk);
  hipMemsetAsync(out, 0, (size_t)out_size*sizeof(float), stream);
  dim3 grid(NB/16, 2), blk(NTHR);
  bilstm_mfma<<<grid, blk, 0, stream>>>(x, bf, bb, pk, out);
}

// Round 9
// 1336.787 us; speedup vs baseline: 1.7050x; 1.7050x over previous
//
#include <hip/hip_runtime.h>

// BiLSTM: B=2048, T=200, D=U=128, 2 layers, bidirectional, merge='ave'.
// R8: R7's single-barrier layer-pipelined schedule (iter t computes L0(t)
// and L1(t-1) in one interval) + R6's non-spilling weight placement:
//   W0,U0,W1 -> 192 VGPRs/lane; U1 -> LDS (staged once, 128KB).
// ks-outer MFMA loop keeps A-frags/U1-frags short-lived: peak regs ~250<256.
// LDS: U1 128K + h0/h1/x dbufs 24K = 152KB. Raw lgkm-only barriers.

#define NB   2048
#define NTT  200
#define ND   128
#define NTHR 512   // 8 waves

typedef _Float16 f16x8 __attribute__((ext_vector_type(8)));
typedef _Float16 f16x4 __attribute__((ext_vector_type(4)));
typedef float    f32x4 __attribute__((ext_vector_type(4)));

#define BARRIER() asm volatile("s_waitcnt lgkmcnt(0)\n\ts_barrier" ::: "memory")

__device__ __forceinline__ float rcp_f(float x){ return __builtin_amdgcn_rcpf(x); }
__device__ __forceinline__ float sigm(float x){ return rcp_f(1.f + __expf(-x)); }
__device__ __forceinline__ float tanh_f(float x){ return 1.f - 2.f*rcp_f(__expf(2.f*x) + 1.f); }

// ---- weight repack to fp16 frags: pk[dir][m][CT][ks][lane][8], m={W0,U0,W1,U1}
// element (lane l, slot j) = src[layer][k][col], k=ks*32+(l>>4)*8+j, col=CT*16+(l&15)
__global__ void __launch_bounds__(256)
repack_w(const float* __restrict__ Wf, const float* __restrict__ Uf,
         const float* __restrict__ Wb, const float* __restrict__ Ub,
         _Float16* __restrict__ pk)
{
  int flat = blockIdx.x*256 + threadIdx.x;        // 0 .. 524287
  int j  = flat & 7;
  int lx = (flat >> 3)  & 63;
  int ks = (flat >> 9)  & 3;
  int CT = (flat >> 11) & 31;
  int m  = (flat >> 16) & 3;
  int dr = (flat >> 18) & 1;
  int k  = ks*32 + (lx >> 4)*8 + j;
  int cc = CT*16 + (lx & 15);
  const float* src = dr ? ((m & 1) ? Ub : Wb) : ((m & 1) ? Uf : Wf);
  int layer = m >> 1;
  pk[flat] = (_Float16)src[((size_t)layer*ND + k)*512 + cc];
}

__global__ void __launch_bounds__(NTHR, 2)
bilstm_mfma(const float* __restrict__ x,
            const float* __restrict__ bf_, const float* __restrict__ bb_,
            const _Float16* __restrict__ pk,
            float* __restrict__ out)
{
  extern __shared__ char smem_raw[];
  _Float16* u1s = (_Float16*)smem_raw;   // 65536 halves (128KB)
  _Float16* h0a = u1s + 65536;           // 2 bufs x 2048 (8KB)
  _Float16* h1a = h0a + 4096;            // 2 bufs x 2048 (8KB)
  _Float16* xb  = h1a + 4096;            // 2 bufs x 2048 (8KB)  total 155648B

  const int tid = threadIdx.x;
  const int dir = blockIdx.y;
  const int b0  = blockIdx.x * 16;
  const int w    = tid >> 6;         // wave 0..7
  const int l    = tid & 63;
  const int col  = l & 15;
  const int kg   = l >> 4;           // 0..3
  const int unit = 16*w + col;

  const f16x8* PKH = (const f16x8*)pk;

  // ---- stage U1 into LDS (once; read-only afterwards)
  {
    const f16x8* u1g = PKH + (size_t)(dir*4 + 3)*32*4*64;
    f16x8* u1d = (f16x8*)u1s;
    for (int idx = tid; idx < 8192; idx += NTHR) u1d[idx] = u1g[idx];
  }

  // ---- resident W0,U0,W1 fragments (192 VGPRs/lane)
  f16x8 w0r[4][4], u0r[4][4], w1r[4][4];   // [i][ks]
  #pragma unroll
  for (int i = 0; i < 4; ++i)
    #pragma unroll
    for (int ks = 0; ks < 4; ++ks){
      w0r[i][ks] = PKH[(size_t)(((dir*4 + 0)*32 + (w + 8*i))*4 + ks)*64 + l];
      u0r[i][ks] = PKH[(size_t)(((dir*4 + 1)*32 + (w + 8*i))*4 + ks)*64 + l];
      w1r[i][ks] = PKH[(size_t)(((dir*4 + 2)*32 + (w + 8*i))*4 + ks)*64 + l];
    }

  const float* Bias = dir ? bb_ : bf_;
  float bia0[4], bia1[4];
  #pragma unroll
  for (int i = 0; i < 4; ++i){
    bia0[i] = Bias[unit + 128*i];
    bia1[i] = Bias[512 + unit + 128*i];
  }

  // zero initial h state (both buffers)
  for (int i = tid; i < 4096; i += NTHR){ h0a[i] = (_Float16)0.f; h1a[i] = (_Float16)0.f; }

  const int er = tid >> 5;           // 0..15
  const int ej = (tid & 31) * 4;     // 0..124
  const size_t xbase = ((size_t)(b0 + er)*NTT)*ND + ej;
  const int xidx = ((ej >> 3) << 7) + (er << 3) + (ej & 7);
  const int hbase = ((unit >> 3) << 7) + (unit & 7);

  // prologue: stage x(t=0) into xb[0]
  {
    const int te0 = dir ? (NTT-1) : 0;
    float4 xv = *(const float4*)(x + xbase + (size_t)te0*ND);
    float vv[4] = {xv.x, xv.y, xv.z, xv.w};
    f16x4 hx;
    #pragma unroll
    for (int q = 0; q < 4; ++q) hx[q] = (_Float16)vv[q];
    *(f16x4*)(xb + xidx) = hx;
  }

  float c0[4] = {0,0,0,0}, c1[4] = {0,0,0,0};

  __syncthreads();

  for (int t = 0; t < NTT; ++t){
    const int te = dir ? (NTT-1-t) : t;
    const int rb = t & 1, wb = rb ^ 1;

    // issue x(t+1) load first (oldest vm op; staged at step end)
    const int tn = (t + 1 < NTT) ? (t + 1) : t;
    const int ten = dir ? (NTT-1-tn) : tn;
    float4 xv = *(const float4*)(x + xbase + (size_t)ten*ND);

    // ---- 64 MFMA, 8 chains: L0(t) and L1(t-1). ks-outer keeps A-frags
    // and U1-frags short-lived (register pressure ~250).
    f32x4 acc0[4], acc1[4];
    #pragma unroll
    for (int i = 0; i < 4; ++i){
      acc0[i] = (f32x4){bia0[i], bia0[i], bia0[i], bia0[i]};
      acc1[i] = (f32x4){bia1[i], bia1[i], bia1[i], bia1[i]};
    }
    const f16x8* u1d = (const f16x8*)u1s;
    #pragma unroll
    for (int ks = 0; ks < 4; ++ks){
      f16x8 ax  = *(const f16x8*)(xb  + rb*2048 + ks*512 + l*8);
      f16x8 ah0 = *(const f16x8*)(h0a + rb*2048 + ks*512 + l*8);
      f16x8 ah1 = *(const f16x8*)(h1a + rb*2048 + ks*512 + l*8);
      #pragma unroll
      for (int i = 0; i < 4; ++i){
        f16x8 u1f = u1d[(size_t)((w + 8*i)*4 + ks)*64 + l];
        acc0[i] = __builtin_amdgcn_mfma_f32_16x16x32_f16(ax , w0r[i][ks], acc0[i], 0, 0, 0);
        acc0[i] = __builtin_amdgcn_mfma_f32_16x16x32_f16(ah0, u0r[i][ks], acc0[i], 0, 0, 0);
        acc1[i] = __builtin_amdgcn_mfma_f32_16x16x32_f16(ah0, w1r[i][ks], acc1[i], 0, 0, 0);
        acc1[i] = __builtin_amdgcn_mfma_f32_16x16x32_f16(ah1, u1f,        acc1[i], 0, 0, 0);
      }
    }

    // ---- cell updates
    #pragma unroll
    for (int q = 0; q < 4; ++q){
      float ig = sigm(acc0[0][q]);
      float fg = sigm(acc0[1][q]);
      float gg = tanh_f(acc0[2][q]);
      float og = sigm(acc0[3][q]);
      float cv = __builtin_fmaf(fg, c0[q], ig*gg);
      c0[q] = cv;
      float hh = og * tanh_f(cv);
      h0a[wb*2048 + hbase + (kg*4 + q)*8] = (_Float16)hh;
    }
    if (t > 0){
      const int teo = dir ? (NTT-t) : (t-1);   // time index t-1
      #pragma unroll
      for (int q = 0; q < 4; ++q){
        float ig = sigm(acc1[0][q]);
        float fg = sigm(acc1[1][q]);
        float gg = tanh_f(acc1[2][q]);
        float og = sigm(acc1[3][q]);
        float cv = __builtin_fmaf(fg, c1[q], ig*gg);
        c1[q] = cv;
        float hh = og * tanh_f(cv);
        h1a[wb*2048 + hbase + (kg*4 + q)*8] = (_Float16)hh;
        atomicAdd(out + ((size_t)(b0 + kg*4 + q)*NTT + teo)*ND + unit, 0.5f*hh);
      }
    }
    // t==0: h1a[wb] stays zero (= h1(-1)), c1 stays 0. acc1 discarded.

    // stage x(t+1) into xb[wb]
    {
      float vv[4] = {xv.x, xv.y, xv.z, xv.w};
      f16x4 hx;
      #pragma unroll
      for (int q = 0; q < 4; ++q) hx[q] = (_Float16)vv[q];
      *(f16x4*)(xb + wb*2048 + xidx) = hx;
    }

    BARRIER();   // single barrier: h0(t), h1(t-1), x(t+1) ready for iter t+1
  }

  // ---- epilogue: L1(NTT-1). After final barrier, h0(NTT-1) and h1(NTT-2)
  // sit in buffers rb = NTT&1 = 0.
  {
    const int rb = NTT & 1;
    f32x4 acc1[4];
    #pragma unroll
    for (int i = 0; i < 4; ++i) acc1[i] = (f32x4){bia1[i], bia1[i], bia1[i], bia1[i]};
    const f16x8* u1d = (const f16x8*)u1s;
    #pragma unroll
    for (int ks = 0; ks < 4; ++ks){
      f16x8 ah0 = *(const f16x8*)(h0a + rb*2048 + ks*512 + l*8);
      f16x8 ah1 = *(const f16x8*)(h1a + rb*2048 + ks*512 + l*8);
      #pragma unroll
      for (int i = 0; i < 4; ++i){
        f16x8 u1f = u1d[(size_t)((w + 8*i)*4 + ks)*64 + l];
        acc1[i] = __builtin_amdgcn_mfma_f32_16x16x32_f16(ah0, w1r[i][ks], acc1[i], 0, 0, 0);
        acc1[i] = __builtin_amdgcn_mfma_f32_16x16x32_f16(ah1, u1f,        acc1[i], 0, 0, 0);
      }
    }
    const int teo = dir ? 0 : (NTT-1);
    #pragma unroll
    for (int q = 0; q < 4; ++q){
      float ig = sigm(acc1[0][q]);
      float fg = sigm(acc1[1][q]);
      float gg = tanh_f(acc1[2][q]);
      float og = sigm(acc1[3][q]);
      float cv = __builtin_fmaf(fg, c1[q], ig*gg);
      float hh = og * tanh_f(cv);
      atomicAdd(out + ((size_t)(b0 + kg*4 + q)*NTT + teo)*ND + unit, 0.5f*hh);
    }
  }
}

extern "C" void kernel_launch(void* const* d_in, const int* in_sizes, int n_in,
                              void* d_out, int out_size, void* d_ws, size_t ws_size,
                              hipStream_t stream)
{
  const float* x  = (const float*)d_in[0];
  const float* Wf = (const float*)d_in[1];
  const float* Uf = (const float*)d_in[2];
  const float* bf = (const float*)d_in[3];
  const float* Wb = (const float*)d_in[4];
  const float* Ub = (const float*)d_in[5];
  const float* bb = (const float*)d_in[6];
  float* out = (float*)d_out;

  _Float16* pk = (_Float16*)d_ws;   // 1 MB packed fp16 weights

  (void)hipFuncSetAttribute((const void*)bilstm_mfma,
                            hipFuncAttributeMaxDynamicSharedMemorySize, 155648);

  repack_w<<<2048, 256, 0, stream>>>(Wf, Uf, Wb, Ub, pk);
  hipMemsetAsync(out, 0, (size_t)out_size*sizeof(float), stream);
  dim3 grid(NB/16, 2), blk(NTHR);
  bilstm_mfma<<<grid, blk, 155648, stream>>>(x, bf, bb, pk, out);
}

// Round 10
// 1176.224 us; speedup vs baseline: 1.9377x; 1.1365x over previous
//
#include <hip/hip_runtime.h>

// BiLSTM: B=2048, T=200, D=U=128, 2 layers, bidirectional, merge='ave'.
// R9: single barrier per step WITHOUT R8's spill: per step run
//   L1(t-1) -> cell1 -> (h1 write, atomics, x-stage)  -> L0(t) -> cell0
// with ONE 16-reg acc set reused sequentially (R8 kept 32 live -> spilled).
// cell1/atomics/x-convert VALU hides under L0's independent MFMAs.
// W0,U0,W1 register-resident (192 regs/lane); U1 LDS-resident (128KB).
// h0/h1/x all double-buffered; 2-step manual unroll makes rb/wb
// compile-time (LDS addr = base+imm); running out/x pointers cut VALU.

#define NB   2048
#define NTT  200
#define ND   128
#define NTHR 512   // 8 waves

typedef _Float16 f16x8 __attribute__((ext_vector_type(8)));
typedef _Float16 f16x4 __attribute__((ext_vector_type(4)));
typedef float    f32x4 __attribute__((ext_vector_type(4)));

#define BARRIER() asm volatile("s_waitcnt lgkmcnt(0)\n\ts_barrier" ::: "memory")

__device__ __forceinline__ float rcp_f(float x){ return __builtin_amdgcn_rcpf(x); }
__device__ __forceinline__ float sigm(float x){ return rcp_f(1.f + __expf(-x)); }
__device__ __forceinline__ float tanh_f(float x){ return 1.f - 2.f*rcp_f(__expf(2.f*x) + 1.f); }

// ---- weight repack to fp16 frags: pk[dir][m][CT][ks][lane][8], m={W0,U0,W1,U1}
// element (lane l, slot j) = src[layer][k][col], k=ks*32+(l>>4)*8+j, col=CT*16+(l&15)
__global__ void __launch_bounds__(256)
repack_w(const float* __restrict__ Wf, const float* __restrict__ Uf,
         const float* __restrict__ Wb, const float* __restrict__ Ub,
         _Float16* __restrict__ pk)
{
  int flat = blockIdx.x*256 + threadIdx.x;        // 0 .. 524287
  int j  = flat & 7;
  int lx = (flat >> 3)  & 63;
  int ks = (flat >> 9)  & 3;
  int CT = (flat >> 11) & 31;
  int m  = (flat >> 16) & 3;
  int dr = (flat >> 18) & 1;
  int k  = ks*32 + (lx >> 4)*8 + j;
  int cc = CT*16 + (lx & 15);
  const float* src = dr ? ((m & 1) ? Ub : Wb) : ((m & 1) ? Uf : Wf);
  int layer = m >> 1;
  pk[flat] = (_Float16)src[((size_t)layer*ND + k)*512 + cc];
}

__global__ void __launch_bounds__(NTHR, 2)
bilstm_mfma(const float* __restrict__ x,
            const float* __restrict__ bf_, const float* __restrict__ bb_,
            const _Float16* __restrict__ pk,
            float* __restrict__ out)
{
  extern __shared__ char smem_raw[];
  _Float16* u1s = (_Float16*)smem_raw;   // 65536 halves (128KB)
  _Float16* h0a = u1s + 65536;           // 2 bufs x 2048 (8KB)
  _Float16* h1a = h0a + 4096;            // 2 bufs x 2048 (8KB)
  _Float16* xb  = h1a + 4096;            // 2 bufs x 2048 (8KB)  total 155648B

  const int tid = threadIdx.x;
  const int dir = blockIdx.y;
  const int b0  = blockIdx.x * 16;
  const int w    = tid >> 6;         // wave 0..7
  const int l    = tid & 63;
  const int col  = l & 15;
  const int kg   = l >> 4;           // 0..3
  const int unit = 16*w + col;

  const f16x8* PKH = (const f16x8*)pk;

  // ---- stage U1 into LDS (once; read-only afterwards)
  {
    const f16x8* u1g = PKH + (size_t)(dir*4 + 3)*32*4*64;
    f16x8* u1d = (f16x8*)u1s;
    for (int idx = tid; idx < 8192; idx += NTHR) u1d[idx] = u1g[idx];
  }

  // ---- resident W0,U0,W1 fragments (192 regs/lane)
  f16x8 w0r[4][4], u0r[4][4], w1r[4][4];   // [i][ks]
  #pragma unroll
  for (int i = 0; i < 4; ++i)
    #pragma unroll
    for (int ks = 0; ks < 4; ++ks){
      w0r[i][ks] = PKH[(size_t)(((dir*4 + 0)*32 + (w + 8*i))*4 + ks)*64 + l];
      u0r[i][ks] = PKH[(size_t)(((dir*4 + 1)*32 + (w + 8*i))*4 + ks)*64 + l];
      w1r[i][ks] = PKH[(size_t)(((dir*4 + 2)*32 + (w + 8*i))*4 + ks)*64 + l];
    }
  const f16x8* u1d = (const f16x8*)u1s;

  const float* Bias = dir ? bb_ : bf_;
  float bia0[4], bia1[4];
  #pragma unroll
  for (int i = 0; i < 4; ++i){
    bia0[i] = Bias[unit + 128*i];
    bia1[i] = Bias[512 + unit + 128*i];
  }

  // zero initial h state (both buffers)
  for (int i = tid; i < 4096; i += NTHR){ h0a[i] = (_Float16)0.f; h1a[i] = (_Float16)0.f; }

  const int er = tid >> 5;           // 0..15
  const int ej = (tid & 31) * 4;     // 0..124
  const int xidx = ((ej >> 3) << 7) + (er << 3) + (ej & 7);
  const int hbase = ((unit >> 3) << 7) + (unit & 7);
  const int dstepN = dir ? -ND : ND;           // elements per step in time dim

  // running pointers
  const float* xrun;                 // points at x(t+1) row for this lane
  {
    const int te0 = dir ? (NTT-1) : 0;
    const float* p0 = x + ((size_t)(b0 + er)*NTT + te0)*ND + ej;
    // prologue: stage x(0) into xb[0]
    float4 xv = *(const float4*)p0;
    float vv[4] = {xv.x, xv.y, xv.z, xv.w};
    f16x4 hx;
    #pragma unroll
    for (int q = 0; q < 4; ++q) hx[q] = (_Float16)vv[q];
    *(f16x4*)(xb + xidx) = hx;
    xrun = p0 + dstepN;
  }
  float* op[4];                      // atomic targets, start at time index 0
  #pragma unroll
  for (int q = 0; q < 4; ++q)
    op[q] = out + ((size_t)(b0 + kg*4 + q)*NTT + (dir ? NTT-1 : 0))*ND + unit;

  float c0[4] = {0,0,0,0}, c1[4] = {0,0,0,0};

  __syncthreads();

  // ---- one step: L1(t-1) [if DO1] then L0(t); single barrier at end.
#define STEP(RB, DO1, DOX)                                                    \
  {                                                                           \
    const int rb = (RB), wb = (RB)^1;                                         \
    float4 xv = make_float4(0,0,0,0);                                         \
    if (DOX) xv = *(const float4*)xrun;                                       \
    f32x4 acc[4];                                                             \
    if (DO1){                                                                 \
      _Pragma("unroll")                                                       \
      for (int i = 0; i < 4; ++i) acc[i] = (f32x4){bia1[i],bia1[i],bia1[i],bia1[i]}; \
      _Pragma("unroll")                                                       \
      for (int ks = 0; ks < 4; ++ks){                                         \
        f16x8 ah0 = *(const f16x8*)(h0a + rb*2048 + ks*512 + l*8);            \
        f16x8 ah1 = *(const f16x8*)(h1a + rb*2048 + ks*512 + l*8);            \
        _Pragma("unroll")                                                     \
        for (int i = 0; i < 4; ++i){                                          \
          f16x8 u1f = u1d[(size_t)((w + 8*i)*4 + ks)*64 + l];                 \
          acc[i] = __builtin_amdgcn_mfma_f32_16x16x32_f16(ah0, w1r[i][ks], acc[i], 0, 0, 0); \
          acc[i] = __builtin_amdgcn_mfma_f32_16x16x32_f16(ah1, u1f,        acc[i], 0, 0, 0); \
        }                                                                     \
      }                                                                       \
      _Pragma("unroll")                                                       \
      for (int q = 0; q < 4; ++q){                                            \
        float ig = sigm(acc[0][q]);                                           \
        float fg = sigm(acc[1][q]);                                           \
        float gg = tanh_f(acc[2][q]);                                         \
        float og = sigm(acc[3][q]);                                           \
        float cv = __builtin_fmaf(fg, c1[q], ig*gg);                          \
        c1[q] = cv;                                                           \
        float hh = og * tanh_f(cv);                                           \
        h1a[wb*2048 + hbase + (kg*4 + q)*8] = (_Float16)hh;                   \
        atomicAdd(op[q], 0.5f*hh);                                            \
        op[q] += dstepN;                                                      \
      }                                                                       \
    }                                                                         \
    if (DOX){                                                                 \
      float vv[4] = {xv.x, xv.y, xv.z, xv.w};                                 \
      f16x4 hx;                                                               \
      _Pragma("unroll")                                                       \
      for (int q = 0; q < 4; ++q) hx[q] = (_Float16)vv[q];                    \
      *(f16x4*)(xb + wb*2048 + xidx) = hx;                                    \
      xrun += dstepN;                                                         \
    }                                                                         \
    _Pragma("unroll")                                                         \
    for (int i = 0; i < 4; ++i) acc[i] = (f32x4){bia0[i],bia0[i],bia0[i],bia0[i]}; \
    _Pragma("unroll")                                                         \
    for (int ks = 0; ks < 4; ++ks){                                           \
      f16x8 axf = *(const f16x8*)(xb  + rb*2048 + ks*512 + l*8);              \
      f16x8 ah0 = *(const f16x8*)(h0a + rb*2048 + ks*512 + l*8);              \
      _Pragma("unroll")                                                       \
      for (int i = 0; i < 4; ++i){                                            \
        acc[i] = __builtin_amdgcn_mfma_f32_16x16x32_f16(axf, w0r[i][ks], acc[i], 0, 0, 0); \
        acc[i] = __builtin_amdgcn_mfma_f32_16x16x32_f16(ah0, u0r[i][ks], acc[i], 0, 0, 0); \
      }                                                                       \
    }                                                                         \
    _Pragma("unroll")                                                         \
    for (int q = 0; q < 4; ++q){                                              \
      float ig = sigm(acc[0][q]);                                             \
      float fg = sigm(acc[1][q]);                                             \
      float gg = tanh_f(acc[2][q]);                                           \
      float og = sigm(acc[3][q]);                                             \
      float cv = __builtin_fmaf(fg, c0[q], ig*gg);                            \
      c0[q] = cv;                                                             \
      float hh = og * tanh_f(cv);                                             \
      h0a[wb*2048 + hbase + (kg*4 + q)*8] = (_Float16)hh;                     \
    }                                                                         \
    BARRIER();                                                                \
  }

  STEP(0, 0, 1)                      // t=0: no L1 (h1(-1)=0 stays in buf 1)
  for (int it = 0; it < 99; ++it){   // t = 1..198 in pairs
    STEP(1, 1, 1)
    STEP(0, 1, 1)
  }
  STEP(1, 1, 0)                      // t=199: no next-x stage

  // ---- epilogue: L1(199). h0(199), h1(198) are in buffers rb=0.
  {
    f32x4 acc[4];
    #pragma unroll
    for (int i = 0; i < 4; ++i) acc[i] = (f32x4){bia1[i],bia1[i],bia1[i],bia1[i]};
    #pragma unroll
    for (int ks = 0; ks < 4; ++ks){
      f16x8 ah0 = *(const f16x8*)(h0a + ks*512 + l*8);
      f16x8 ah1 = *(const f16x8*)(h1a + ks*512 + l*8);
      #pragma unroll
      for (int i = 0; i < 4; ++i){
        f16x8 u1f = u1d[(size_t)((w + 8*i)*4 + ks)*64 + l];
        acc[i] = __builtin_amdgcn_mfma_f32_16x16x32_f16(ah0, w1r[i][ks], acc[i], 0, 0, 0);
        acc[i] = __builtin_amdgcn_mfma_f32_16x16x32_f16(ah1, u1f,        acc[i], 0, 0, 0);
      }
    }
    #pragma unroll
    for (int q = 0; q < 4; ++q){
      float ig = sigm(acc[0][q]);
      float fg = sigm(acc[1][q]);
      float gg = tanh_f(acc[2][q]);
      float og = sigm(acc[3][q]);
      float cv = __builtin_fmaf(fg, c1[q], ig*gg);
      float hh = og * tanh_f(cv);
      atomicAdd(op[q], 0.5f*hh);
    }
  }
#undef STEP
}

extern "C" void kernel_launch(void* const* d_in, const int* in_sizes, int n_in,
                              void* d_out, int out_size, void* d_ws, size_t ws_size,
                              hipStream_t stream)
{
  const float* x  = (const float*)d_in[0];
  const float* Wf = (const float*)d_in[1];
  const float* Uf = (const float*)d_in[2];
  const float* bf = (const float*)d_in[3];
  const float* Wb = (const float*)d_in[4];
  const float* Ub = (const float*)d_in[5];
  const float* bb = (const float*)d_in[6];
  float* out = (float*)d_out;

  _Float16* pk = (_Float16*)d_ws;   // 1 MB packed fp16 weights

  (void)hipFuncSetAttribute((const void*)bilstm_mfma,
                            hipFuncAttributeMaxDynamicSharedMemorySize, 155648);

  repack_w<<<2048, 256, 0, stream>>>(Wf, Uf, Wb, Ub, pk);
  hipMemsetAsync(out, 0, (size_t)out_size*sizeof(float), stream);
  dim3 grid(NB/16, 2), blk(NTHR);
  bilstm_mfma<<<grid, blk, 155648, stream>>>(x, bf, bb, pk, out);
}

// Round 11
// 895.054 us; speedup vs baseline: 2.5464x; 1.3141x over previous
//
#include <hip/hip_runtime.h>

// BiLSTM: B=2048, T=200, D=U=128, 2 layers, bidirectional, merge='ave'.
// R10: single barrier/step (L1(t-1) then L0(t), one 16-reg acc set reused)
// with R6's register footprint restored:
//  - ONE step body (runtime rb, unroll-disabled) -> no I$ thrash/code bloat
//  - 32-bit element offsets (obase/xoff) + uniform teN -> no pointer arrays
//  - x load issued AFTER the L1 MFMA block (off the L1 register peak)
// W0,U0,W1 register-resident (192 regs/lane); U1 LDS-resident (128KB).
// LDS: U1 128K + h0/h1/x dbufs 24K = 152KB. Raw lgkm-only barriers.

#define NB   2048
#define NTT  200
#define ND   128
#define NTHR 512   // 8 waves

typedef _Float16 f16x8 __attribute__((ext_vector_type(8)));
typedef _Float16 f16x4 __attribute__((ext_vector_type(4)));
typedef float    f32x4 __attribute__((ext_vector_type(4)));

#define BARRIER() asm volatile("s_waitcnt lgkmcnt(0)\n\ts_barrier" ::: "memory")
#define MFMA16(A,B,C) __builtin_amdgcn_mfma_f32_16x16x32_f16((A),(B),(C),0,0,0)

__device__ __forceinline__ float rcp_f(float x){ return __builtin_amdgcn_rcpf(x); }
__device__ __forceinline__ float sigm(float x){ return rcp_f(1.f + __expf(-x)); }
__device__ __forceinline__ float tanh_f(float x){ return 1.f - 2.f*rcp_f(__expf(2.f*x) + 1.f); }

// ---- weight repack to fp16 frags: pk[dir][m][CT][ks][lane][8], m={W0,U0,W1,U1}
// element (lane l, slot j) = src[layer][k][col], k=ks*32+(l>>4)*8+j, col=CT*16+(l&15)
__global__ void __launch_bounds__(256)
repack_w(const float* __restrict__ Wf, const float* __restrict__ Uf,
         const float* __restrict__ Wb, const float* __restrict__ Ub,
         _Float16* __restrict__ pk)
{
  int flat = blockIdx.x*256 + threadIdx.x;        // 0 .. 524287
  int j  = flat & 7;
  int lx = (flat >> 3)  & 63;
  int ks = (flat >> 9)  & 3;
  int CT = (flat >> 11) & 31;
  int m  = (flat >> 16) & 3;
  int dr = (flat >> 18) & 1;
  int k  = ks*32 + (lx >> 4)*8 + j;
  int cc = CT*16 + (lx & 15);
  const float* src = dr ? ((m & 1) ? Ub : Wb) : ((m & 1) ? Uf : Wf);
  int layer = m >> 1;
  pk[flat] = (_Float16)src[((size_t)layer*ND + k)*512 + cc];
}

__global__ void __launch_bounds__(NTHR, 2)
bilstm_mfma(const float* __restrict__ x,
            const float* __restrict__ bf_, const float* __restrict__ bb_,
            const _Float16* __restrict__ pk,
            float* __restrict__ out)
{
  extern __shared__ char smem_raw[];
  _Float16* u1s = (_Float16*)smem_raw;   // 65536 halves (128KB)
  _Float16* h0a = u1s + 65536;           // 2 bufs x 2048 (8KB)
  _Float16* h1a = h0a + 4096;            // 2 bufs x 2048 (8KB)
  _Float16* xb  = h1a + 4096;            // 2 bufs x 2048 (8KB)  total 152KB

  const int tid = threadIdx.x;
  const int dir = blockIdx.y;
  const int b0  = blockIdx.x * 16;
  const int w    = tid >> 6;         // wave 0..7
  const int l    = tid & 63;
  const int col  = l & 15;
  const int kg   = l >> 4;           // 0..3
  const int unit = 16*w + col;

  const f16x8* PKH = (const f16x8*)pk;

  // ---- stage U1 into LDS (once; read-only afterwards)
  {
    const f16x8* u1g = PKH + (size_t)(dir*4 + 3)*32*4*64;
    f16x8* u1w = (f16x8*)u1s;
    for (int idx = tid; idx < 8192; idx += NTHR) u1w[idx] = u1g[idx];
  }

  // ---- resident W0,U0,W1 fragments (192 regs/lane)
  f16x8 w0r[4][4], u0r[4][4], w1r[4][4];   // [i][ks]
  #pragma unroll
  for (int i = 0; i < 4; ++i)
    #pragma unroll
    for (int ks = 0; ks < 4; ++ks){
      w0r[i][ks] = PKH[(size_t)(((dir*4 + 0)*32 + (w + 8*i))*4 + ks)*64 + l];
      u0r[i][ks] = PKH[(size_t)(((dir*4 + 1)*32 + (w + 8*i))*4 + ks)*64 + l];
      w1r[i][ks] = PKH[(size_t)(((dir*4 + 2)*32 + (w + 8*i))*4 + ks)*64 + l];
    }
  const f16x8* u1d = (const f16x8*)u1s;

  const float* Bias = dir ? bb_ : bf_;
  float bia0[4], bia1[4];
  #pragma unroll
  for (int i = 0; i < 4; ++i){
    bia0[i] = Bias[unit + 128*i];
    bia1[i] = Bias[512 + unit + 128*i];
  }

  // zero initial h state (both buffers)
  for (int i = tid; i < 4096; i += NTHR){ h0a[i] = (_Float16)0.f; h1a[i] = (_Float16)0.f; }

  const int er = tid >> 5;           // 0..15
  const int ej = (tid & 31) * 4;     // 0..124
  const int xidx  = ((ej >> 3) << 7) + (er << 3) + (ej & 7);
  const int hbase = ((unit >> 3) << 7) + (unit & 7);
  const int dstepN = dir ? -ND : ND;

  // 32-bit element offsets (out is 210MB, x is 196MB: fits unsigned)
  unsigned xoff  = (unsigned)(((b0 + er)*NTT + (dir ? NTT-2 : 1))*ND + ej); // x row for t=1
  const unsigned obase = (unsigned)((b0 + kg*4)*NTT*ND + unit);             // q=0, te=0
  int teN = (dir ? (NTT-1) : 0) * ND;  // uniform te(t)*ND (SGPR)

  // prologue: stage x(0) into xb buf0
  {
    float4 xv = *(const float4*)(x + (xoff - dstepN));
    f16x4 hx;
    hx[0]=(_Float16)xv.x; hx[1]=(_Float16)xv.y; hx[2]=(_Float16)xv.z; hx[3]=(_Float16)xv.w;
    *(f16x4*)(xb + xidx) = hx;
  }

  float c0[4] = {0,0,0,0}, c1[4] = {0,0,0,0};

  __syncthreads();

  #pragma clang loop unroll(disable)
  for (int t = 0; t < NTT; ++t){
    const int rbo = (t & 1) << 11;     // read-buffer half offset (halves)
    const int wbo = rbo ^ 2048;        // write-buffer half offset

    f32x4 acc[4];

    // ---------- L1(t-1): z = b1 + h0(t-1)@W1 + h1(t-2)@U1
    if (t > 0){
      #pragma unroll
      for (int i = 0; i < 4; ++i) acc[i] = (f32x4){bia1[i],bia1[i],bia1[i],bia1[i]};
      #pragma unroll
      for (int ks = 0; ks < 4; ++ks){
        f16x8 ah0 = *(const f16x8*)(h0a + rbo + ks*512 + l*8);
        f16x8 ah1 = *(const f16x8*)(h1a + rbo + ks*512 + l*8);
        #pragma unroll
        for (int i = 0; i < 4; ++i){
          f16x8 u1f = u1d[((w + 8*i)*4 + ks)*64 + l];
          acc[i] = MFMA16(ah0, w1r[i][ks], acc[i]);
          acc[i] = MFMA16(ah1, u1f,        acc[i]);
        }
      }
    }

    // issue x(t+1) load (consumed at step end; off the L1 register peak)
    float4 xv = *(const float4*)(x + xoff);
    if (t + 2 < NTT) xoff += dstepN;   // clamp: t=199 re-reads row 199 (unused)

    if (t > 0){
      const int teoN = teN - dstepN;   // te(t-1)*ND, uniform
      #pragma unroll
      for (int q = 0; q < 4; ++q){
        float ig = sigm(acc[0][q]);
        float fg = sigm(acc[1][q]);
        float gg = tanh_f(acc[2][q]);
        float og = sigm(acc[3][q]);
        float cv = __builtin_fmaf(fg, c1[q], ig*gg);
        c1[q] = cv;
        float hh = og * tanh_f(cv);
        h1a[wbo + hbase + (kg*4 + q)*8] = (_Float16)hh;
        atomicAdd(out + (obase + (unsigned)(q*NTT*ND) + (unsigned)teoN), 0.5f*hh);
      }
    }
    // t==0: h1a[wbo] stays zero (= h1(-1)); c1 stays 0.

    // ---------- L0(t): z = b0 + x(t)@W0 + h0(t-1)@U0 (all-register weights)
    #pragma unroll
    for (int i = 0; i < 4; ++i) acc[i] = (f32x4){bia0[i],bia0[i],bia0[i],bia0[i]};
    #pragma unroll
    for (int ks = 0; ks < 4; ++ks){
      f16x8 axf = *(const f16x8*)(xb  + rbo + ks*512 + l*8);
      f16x8 ah0 = *(const f16x8*)(h0a + rbo + ks*512 + l*8);
      #pragma unroll
      for (int i = 0; i < 4; ++i){
        acc[i] = MFMA16(axf, w0r[i][ks], acc[i]);
        acc[i] = MFMA16(ah0, u0r[i][ks], acc[i]);
      }
    }
    #pragma unroll
    for (int q = 0; q < 4; ++q){
      float ig = sigm(acc[0][q]);
      float fg = sigm(acc[1][q]);
      float gg = tanh_f(acc[2][q]);
      float og = sigm(acc[3][q]);
      float cv = __builtin_fmaf(fg, c0[q], ig*gg);
      c0[q] = cv;
      float hh = og * tanh_f(cv);
      h0a[wbo + hbase + (kg*4 + q)*8] = (_Float16)hh;
    }

    // stage x(t+1) into xb[wbo]
    {
      f16x4 hx;
      hx[0]=(_Float16)xv.x; hx[1]=(_Float16)xv.y; hx[2]=(_Float16)xv.z; hx[3]=(_Float16)xv.w;
      *(f16x4*)(xb + wbo + xidx) = hx;
    }

    BARRIER();   // single barrier: h0(t), h1(t-1), x(t+1) ready for iter t+1
    teN += dstepN;
  }

  // ---- epilogue: L1(NTT-1). h0(199), h1(198) are in buffers rb = NTT&1 = 0.
  {
    f32x4 acc[4];
    #pragma unroll
    for (int i = 0; i < 4; ++i) acc[i] = (f32x4){bia1[i],bia1[i],bia1[i],bia1[i]};
    #pragma unroll
    for (int ks = 0; ks < 4; ++ks){
      f16x8 ah0 = *(const f16x8*)(h0a + ks*512 + l*8);
      f16x8 ah1 = *(const f16x8*)(h1a + ks*512 + l*8);
      #pragma unroll
      for (int i = 0; i < 4; ++i){
        f16x8 u1f = u1d[((w + 8*i)*4 + ks)*64 + l];
        acc[i] = MFMA16(ah0, w1r[i][ks], acc[i]);
        acc[i] = MFMA16(ah1, u1f,        acc[i]);
      }
    }
    const int teoN = teN - dstepN;     // = te(199)*ND
    #pragma unroll
    for (int q = 0; q < 4; ++q){
      float ig = sigm(acc[0][q]);
      float fg = sigm(acc[1][q]);
      float gg = tanh_f(acc[2][q]);
      float og = sigm(acc[3][q]);
      float cv = __builtin_fmaf(fg, c1[q], ig*gg);
      float hh = og * tanh_f(cv);
      atomicAdd(out + (obase + (unsigned)(q*NTT*ND) + (unsigned)teoN), 0.5f*hh);
    }
  }
}

extern "C" void kernel_launch(void* const* d_in, const int* in_sizes, int n_in,
                              void* d_out, int out_size, void* d_ws, size_t ws_size,
                              hipStream_t stream)
{
  const float* x  = (const float*)d_in[0];
  const float* Wf = (const float*)d_in[1];
  const float* Uf = (const float*)d_in[2];
  const float* bf = (const float*)d_in[3];
  const float* Wb = (const float*)d_in[4];
  const float* Ub = (const float*)d_in[5];
  const float* bb = (const float*)d_in[6];
  float* out = (float*)d_out;

  _Float16* pk = (_Float16*)d_ws;   // 1 MB packed fp16 weights

  (void)hipFuncSetAttribute((const void*)bilstm_mfma,
                            hipFuncAttributeMaxDynamicSharedMemorySize, 155648);

  repack_w<<<2048, 256, 0, stream>>>(Wf, Uf, Wb, Ub, pk);
  hipMemsetAsync(out, 0, (size_t)out_size*sizeof(float), stream);
  dim3 grid(NB/16, 2), blk(NTHR);
  bilstm_mfma<<<grid, blk, 155648, stream>>>(x, bf, bb, pk, out);
}